// Round 15
// baseline (83.051 us; speedup 1.0000x reference)
//
#include <hip/hip_runtime.h>
#include <hip/hip_bf16.h>

typedef float f32x4 __attribute__((ext_vector_type(4)));
typedef short bf16x8 __attribute__((ext_vector_type(8)));
typedef unsigned short us4 __attribute__((ext_vector_type(4)));

#define NB 16
#define NC 256
#define NTOK 4096
#define NHID 128

// ---- hw bf16 converts (compiler emits v_cvt_pk_bf16_f32) ----
__device__ __forceinline__ unsigned pk2(float lo, float hi) {
  float2 f; f.x = lo; f.y = hi;
  __hip_bfloat162 h = __float22bfloat162_rn(f);
  unsigned u; __builtin_memcpy(&u, &h, 4); return u;
}
__device__ __forceinline__ uint2 pk4(f32x4 v) {
  uint2 r; r.x = pk2(v[0], v[1]); r.y = pk2(v[2], v[3]); return r;
}
__device__ __forceinline__ float bf2f(unsigned short h) {
  union { unsigned u; float f; } v; v.u = ((unsigned)h) << 16;
  return v.f;
}

// ---------------------------------------------------------------------------
// k0: W rows (Wq|Wk|Wv, fp32) -> bf16 MFMA frag per-lane order.
// Frag (mt, ks): lane l holds W[mt*16 + (l&15)][ks*32 + (l>>4)*8 .. +8].
// (Layout serves as BOTH A- and B-operand: the 16x16x32 frag is lane-symmetric.)
// ---------------------------------------------------------------------------
__global__ __launch_bounds__(512) void k0_w(
    const float* __restrict__ Wq, const float* __restrict__ Wk,
    const float* __restrict__ Wv, unsigned short* __restrict__ Wswz)
{
  const int mt = blockIdx.x;            // 0..23
  const int t = threadIdx.x;
  const int ks = t >> 6, l = t & 63;
  const int m = mt * 16 + (l & 15);
  const int col = ks * 32 + (l >> 4) * 8;
  const float* src = (m < 128) ? (Wq + (size_t)m * NC)
                   : (m < 256) ? (Wk + (size_t)(m - 128) * NC)
                               : (Wv + (size_t)(m - 256) * NC);
  const float4 w0 = *(const float4*)(src + col);
  const float4 w1 = *(const float4*)(src + col + 4);
  uint4 p;
  p.x = pk2(w0.x, w0.y); p.y = pk2(w0.z, w0.w);
  p.z = pk2(w1.x, w1.y); p.w = pk2(w1.z, w1.w);
  *(uint4*)&Wswz[((size_t)(mt * 8 + ks)) * 512 + l * 8] = p;
}

// ---------------------------------------------------------------------------
// k1: per (b, 64-token tile). LDS 64 KB: As (32 KB) + separate postKV (32 KB).
// Depth-2 W prefetch, hoisted initial W loads. (512,4): no spill.
// q-waves use SWAPPED MFMA operands (D[j][tok]): head-dim softmax is
// lane-local + 2 shuffles per token-frag (was 16 chains x 8 shuffles),
// no max-subtraction (q ~ N(0,1), exp fp32-safe, softmax shift-invariant).
// qg layout: [tile][tf panel][tok(16)][j(128)] bf16, j-offset XOR-preswizzled
// by ((tok&7)<<4) bytes so k3 can ds_read_b128 conflict-free after a linear
// global_load_lds stage.
// ---------------------------------------------------------------------------
__global__ __launch_bounds__(512, 4) void k1_qkv(
    const float* __restrict__ x, const unsigned short* __restrict__ Wswz,
    unsigned short* __restrict__ qg, unsigned short* __restrict__ Pp,
    float* __restrict__ Sp)
{
  __shared__ __align__(16) unsigned char smem[65536];
  // [0, 32768):      As [64 tok][512 B], XOR ^((tok&7)<<4)
  // [32768, 65536):  postKV [256 rows][128 B], XOR ^((row&7)<<4)

  const int tile = blockIdx.x, b = blockIdx.y;
  const int n0 = tile * 64;
  const int t = threadIdx.x;
  const int wid = t >> 6, l = t & 63;
  const int l16 = l & 15, lhi = l >> 4;
  const unsigned xr = (unsigned)((l16 & 7) << 4);

  int fr[3];
  if (wid < 4) { fr[0] = 2 * wid; fr[1] = 2 * wid + 1; fr[2] = 8 + wid; }
  else { const int w = wid - 4; fr[0] = 12 + w; fr[1] = 16 + 2 * w; fr[2] = 17 + 2 * w; }

#define WFRAG(f, kss) (*(const bf16x8*)&Wswz[((size_t)(fr[f] * 8 + (kss))) * 512 + l * 8])
#define AFRAG(tf, kss) (*(const bf16x8*)(smem + \
    (((unsigned)(((tf) * 16 + l16) * 512 + (kss) * 64 + lhi * 16)) ^ xr)))
#define PKVB(roww, boff) (smem + 32768u + \
    ((((unsigned)((roww) * 128 + (boff))) ^ (((unsigned)((roww) & 7)) << 4))))

  // ---- hoisted initial W-frag loads (land during x-stage + barrier)
  bf16x8 wA[3], wB[3], wC[3];
#pragma unroll
  for (int f = 0; f < 3; ++f) wA[f] = WFRAG(f, 0);
#pragma unroll
  for (int f = 0; f < 3; ++f) wB[f] = WFRAG(f, 1);

  // ---- stage x^T tile -> As[tok][c] bf16, XOR swizzled, b128 writes
  {
    const int cg = t >> 4;   // 8-c group 0..31
    const int tq = t & 15;   // tok quad
    const float* rp = x + (size_t)b * NC * NTOK + (size_t)(cg * 8) * NTOK + n0 + tq * 4;
    float4 rv[8];
#pragma unroll
    for (int i = 0; i < 8; ++i) rv[i] = *(const float4*)(rp + (size_t)i * NTOK);
#pragma unroll
    for (int j = 0; j < 4; ++j) {
      const int tok = tq * 4 + j;
      uint4 pv;
      pv.x = pk2(rv[0][j], rv[1][j]); pv.y = pk2(rv[2][j], rv[3][j]);
      pv.z = pk2(rv[4][j], rv[5][j]); pv.w = pk2(rv[6][j], rv[7][j]);
      *(uint4*)(smem + (((unsigned)(tok * 512 + cg * 16)) ^ ((unsigned)(tok & 7) << 4))) = pv;
    }
  }
  __syncthreads();

  // ---- GEMM: 64 toks x 3 m-frags per wave, K=256, depth-2 W prefetch.
  // q-waves: frags 0,1 swapped (D[j][tok]); frag 2 (k) normal (D[tok][j]).
  f32x4 acc[4][3];
#pragma unroll
  for (int i = 0; i < 4; ++i)
#pragma unroll
    for (int j = 0; j < 3; ++j) acc[i][j] = 0;

  if (wid < 4) {
#pragma unroll
    for (int ks = 0; ks < 8; ++ks) {
      if (ks < 6) {
#pragma unroll
        for (int f = 0; f < 3; ++f) wC[f] = WFRAG(f, ks + 2);
      }
#pragma unroll
      for (int tf = 0; tf < 4; ++tf) {
        const bf16x8 a = AFRAG(tf, ks);
        acc[tf][0] = __builtin_amdgcn_mfma_f32_16x16x32_bf16(wA[0], a, acc[tf][0], 0, 0, 0);
        acc[tf][1] = __builtin_amdgcn_mfma_f32_16x16x32_bf16(wA[1], a, acc[tf][1], 0, 0, 0);
        acc[tf][2] = __builtin_amdgcn_mfma_f32_16x16x32_bf16(a, wA[2], acc[tf][2], 0, 0, 0);
      }
#pragma unroll
      for (int f = 0; f < 3; ++f) { wA[f] = wB[f]; wB[f] = wC[f]; }
    }
  } else {
#pragma unroll
    for (int ks = 0; ks < 8; ++ks) {
      if (ks < 6) {
#pragma unroll
        for (int f = 0; f < 3; ++f) wC[f] = WFRAG(f, ks + 2);
      }
#pragma unroll
      for (int tf = 0; tf < 4; ++tf) {
        const bf16x8 a = AFRAG(tf, ks);
#pragma unroll
        for (int f = 0; f < 3; ++f)
          acc[tf][f] = __builtin_amdgcn_mfma_f32_16x16x32_bf16(a, wA[f], acc[tf][f], 0, 0, 0);
      }
#pragma unroll
      for (int f = 0; f < 3; ++f) { wA[f] = wB[f]; wB[f] = wC[f]; }
    }
  }

  // ---- register epilogue; retire to postKV / global
  const float qscale = 0.1767766952966369f;  // 32^-0.5
  if (wid < 4) {
    // q: swapped layout. Lane holds j = fr[f]*16 + lhi*4 + r for tok = l16.
    // Softmax over 32 j's: 8 lane-local exp+add, then reduce across lhi.
    unsigned char* qt = (unsigned char*)(qg + ((size_t)(b * 64 + tile)) * 8192);
#pragma unroll
    for (int tf = 0; tf < 4; ++tf) {
      float ex[2][4];
      float s = 0.f;
#pragma unroll
      for (int f = 0; f < 2; ++f)
#pragma unroll
        for (int r = 0; r < 4; ++r) {
          ex[f][r] = __expf(acc[tf][f][r]);
          s += ex[f][r];
        }
      s += __shfl_xor(s, 16);
      s += __shfl_xor(s, 32);
      const float inv = qscale / s;
#pragma unroll
      for (int f = 0; f < 2; ++f) {
        f32x4 v;
#pragma unroll
        for (int r = 0; r < 4; ++r) v[r] = ex[f][r] * inv;
        const unsigned boff = ((unsigned)(fr[f] * 32 + lhi * 8)) ^ xr;
        *(uint2*)(qt + tf * 4096 + l16 * 256 + boff) = pk4(v);
      }
    }
    // k frag (normal layout): exp + full-tile column sum + postKV
    float s = 0.f;
#pragma unroll
    for (int tf = 0; tf < 4; ++tf)
#pragma unroll
      for (int r = 0; r < 4; ++r) {
        const float e = __expf(acc[tf][2][r]);
        acc[tf][2][r] = e;
        s += e;
      }
    s += __shfl_xor(s, 16);
    s += __shfl_xor(s, 32);
    if (l < 16) Sp[((size_t)b * 64 + tile) * 128 + (fr[2] - 8) * 16 + l16] = s;

    const int row = (fr[2] - 8) * 16 + l16;
#pragma unroll
    for (int tf = 0; tf < 4; ++tf)
      *(uint2*)PKVB(row, tf * 32 + lhi * 8) = pk4(acc[tf][2]);
  } else {
    float s = 0.f;
#pragma unroll
    for (int tf = 0; tf < 4; ++tf)
#pragma unroll
      for (int r = 0; r < 4; ++r) {
        const float e = __expf(acc[tf][0][r]);
        acc[tf][0][r] = e;
        s += e;
      }
    s += __shfl_xor(s, 16);
    s += __shfl_xor(s, 32);
    if (l < 16) Sp[((size_t)b * 64 + tile) * 128 + (fr[0] - 8) * 16 + l16] = s;

    const int rowk = (fr[0] - 8) * 16 + l16;
    const int rowv1 = 128 + (fr[1] - 16) * 16 + l16;
    const int rowv2 = 128 + (fr[2] - 16) * 16 + l16;
#pragma unroll
    for (int tf = 0; tf < 4; ++tf) {
      *(uint2*)PKVB(rowk, tf * 32 + lhi * 8) = pk4(acc[tf][0]);
      *(uint2*)PKVB(rowv1, tf * 32 + lhi * 8) = pk4(acc[tf][1]);
      *(uint2*)PKVB(rowv2, tf * 32 + lhi * 8) = pk4(acc[tf][2]);
    }
  }
  __syncthreads();  // postKV complete

  // ---- context partials: all 8 waves, wave = (h = wid&3, d-half = wid>>2)
  {
    const int h = wid & 3, dh = wid >> 2;
    f32x4 ca[2];
    ca[0] = 0; ca[1] = 0;
#pragma unroll
    for (int ks2 = 0; ks2 < 2; ++ks2) {
      const int rowa = h * 32 + dh * 16 + l16;
      const bf16x8 ae = *(const bf16x8*)PKVB(rowa, ks2 * 64 + lhi * 16);
#pragma unroll
      for (int e = 0; e < 2; ++e) {
        const int rowb = 128 + h * 32 + e * 16 + l16;
        const bf16x8 be = *(const bf16x8*)PKVB(rowb, ks2 * 64 + lhi * 16);
        ca[e] = __builtin_amdgcn_mfma_f32_16x16x32_bf16(ae, be, ca[e], 0, 0, 0);
      }
    }
    unsigned short* pb = Pp + (((size_t)b * 64 + tile) * 4 + h) * 1024;
#pragma unroll
    for (int e = 0; e < 2; ++e)
      *(uint2*)&pb[(e * 16 + l16) * 32 + dh * 16 + lhi * 4] = pk4(ca[e]);
  }
}

// ---------------------------------------------------------------------------
// k2a: tree stage 1. Grid (8 seg, 16 b).
// ---------------------------------------------------------------------------
__global__ __launch_bounds__(256) void k2a_tree(
    const unsigned short* __restrict__ Pp, const float* __restrict__ Sp,
    float* __restrict__ Pr, float* __restrict__ Sr)
{
  const int seg = blockIdx.x, b = blockIdx.y;
  const int t = threadIdx.x;
  const unsigned short* pb = Pp + ((size_t)b * 64 + seg * 8) * 4096;
  f32x4 a[4];
#pragma unroll
  for (int i = 0; i < 4; ++i) a[i] = 0;
#pragma unroll
  for (int tile = 0; tile < 8; ++tile) {
#pragma unroll
    for (int i = 0; i < 4; ++i) {
      const us4 v = *(const us4*)&pb[tile * 4096 + i * 1024 + t * 4];
      a[i][0] += bf2f(v[0]); a[i][1] += bf2f(v[1]);
      a[i][2] += bf2f(v[2]); a[i][3] += bf2f(v[3]);
    }
  }
  float* pr = Pr + ((size_t)b * 8 + seg) * 4096;
#pragma unroll
  for (int i = 0; i < 4; ++i) *(f32x4*)&pr[i * 1024 + t * 4] = a[i];

  if (t < 128) {
    float s = 0.f;
    const float* sb = Sp + ((size_t)b * 64 + seg * 8) * 128 + t;
#pragma unroll
    for (int i = 0; i < 8; ++i) s += sb[i * 128];
    Sr[((size_t)b * 8 + seg) * 128 + t] = s;
  }
}

// ---------------------------------------------------------------------------
// k2bc: tree stage 2 + normalize + M build. Grid (16 ct, 16 b).
// ---------------------------------------------------------------------------
__global__ __launch_bounds__(256) void k2bc(
    const float* __restrict__ Pr, const float* __restrict__ Sr,
    const float* __restrict__ Wo, unsigned short* __restrict__ Mswz)
{
  __shared__ float CnS[4096];
  __shared__ float Ss[128];
  const int ct = blockIdx.x, b = blockIdx.y;
  const int t = threadIdx.x;

  if (t < 128) {
    float s = 0.f;
    const float* sb = Sr + (size_t)b * 8 * 128 + t;
#pragma unroll
    for (int i = 0; i < 8; ++i) s += sb[i * 128];
    Ss[t] = 1.0f / (s * 4096.0f);
  }
  __syncthreads();

#pragma unroll
  for (int i = 0; i < 16; ++i) {
    const int idx = t + 256 * i;
    float a = 0.f;
#pragma unroll
    for (int seg = 0; seg < 8; ++seg) a += Pr[((size_t)b * 8 + seg) * 4096 + idx];
    CnS[idx] = a * Ss[((idx >> 10) << 5) | (idx & 31)];
  }
  __syncthreads();

  const int ks = t >> 6, l = t & 63;  // ks = h
  const int c = ct * 16 + (l & 15);
  const int d0 = (l >> 4) * 8;
  const float* wr = Wo + (size_t)c * NHID + ks * 32;
  const float* cb = &CnS[ks * 1024];
  f32x4 s0 = 0, s1 = 0;
#pragma unroll 8
  for (int e = 0; e < 32; ++e) {
    const float w = wr[e];
    const f32x4 c0 = *(const f32x4*)&cb[e * 32 + d0];
    const f32x4 c1 = *(const f32x4*)&cb[e * 32 + d0 + 4];
#pragma unroll
    for (int j = 0; j < 4; ++j) { s0[j] += w * c0[j]; s1[j] += w * c1[j]; }
  }
  uint4 p;
  p.x = pk2(s0[0], s0[1]); p.y = pk2(s0[2], s0[3]);
  p.z = pk2(s1[0], s1[1]); p.w = pk2(s1[2], s1[3]);
  *(uint4*)&Mswz[(((size_t)b * 16 + ct) * 4 + ks) * 512 + l * 8] = p;
}

// ---------------------------------------------------------------------------
// k3: out[b][c][n] = LN_c( sum_j M[c][j] q[n][j] + bo[c] ) * g[c]
// One tile/block, grid (64,16). qg is [tf][tok][j] with XOR-preswizzled j,
// staged linearly via global_load_lds; A-frags are single conflict-free
// ds_read_b128 (was 8 scalar u16 gathers per frag).
// ---------------------------------------------------------------------------
__global__ __launch_bounds__(256, 3) void k3_out(
    const unsigned short* __restrict__ qg, const unsigned short* __restrict__ Mswz,
    const float* __restrict__ bo, const float* __restrict__ g, float* __restrict__ out)
{
  __shared__ __align__(16) unsigned char qs[16384];
  __shared__ float red[4 * 64 * 2];
  const int bx = blockIdx.x, b = blockIdx.y;
  const int t = threadIdx.x;
  const int wid = t >> 6, l = t & 63;
  const int l16 = l & 15, lhi = l >> 4;
  const unsigned xr = (unsigned)((l16 & 7) << 4);

  // async stage q tile (16 KB): per (wave, chunk), lds = base + lane*16
  {
    const unsigned char* gq = (const unsigned char*)(qg + ((size_t)(b * 64 + bx)) * 8192);
#pragma unroll
    for (int i = 0; i < 4; ++i)
      __builtin_amdgcn_global_load_lds(
          (const unsigned int*)(gq + i * 4096 + (wid * 64 + l) * 16),
          (unsigned int*)(qs + i * 4096 + wid * 1024),
          16, 0, 0);
  }

  bf16x8 mf[4][4];
#pragma unroll
  for (int cf = 0; cf < 4; ++cf)
#pragma unroll
    for (int ks = 0; ks < 4; ++ks)
      mf[cf][ks] = *(const bf16x8*)&Mswz[(((size_t)b * 16 + wid * 4 + cf) * 4 + ks) * 512 + l * 8];

  float bol[4], gl[4];
#pragma unroll
  for (int cf = 0; cf < 4; ++cf) {
    const int c = wid * 64 + cf * 16 + l16;
    bol[cf] = bo[c]; gl[cf] = g[c];
  }

  f32x4 acc[4][4];
#pragma unroll
  for (int i = 0; i < 4; ++i)
#pragma unroll
    for (int j = 0; j < 4; ++j) acc[i][j] = 0;

  __syncthreads();  // qs staged (vmcnt drained by barrier)

#pragma unroll
  for (int tf = 0; tf < 4; ++tf) {
    bf16x8 qf[4];
#pragma unroll
    for (int ks = 0; ks < 4; ++ks)
      qf[ks] = *(const bf16x8*)(qs + tf * 4096 + l16 * 256 +
                  (((unsigned)(ks * 64 + lhi * 16)) ^ xr));
#pragma unroll
    for (int ks = 0; ks < 4; ++ks)
#pragma unroll
      for (int cf = 0; cf < 4; ++cf)
        acc[tf][cf] = __builtin_amdgcn_mfma_f32_16x16x32_bf16(qf[ks], mf[cf][ks], acc[tf][cf], 0, 0, 0);
  }

#pragma unroll
  for (int tf = 0; tf < 4; ++tf)
#pragma unroll
    for (int cf = 0; cf < 4; ++cf)
#pragma unroll
      for (int r = 0; r < 4; ++r) acc[tf][cf][r] += bol[cf];

  __syncthreads();  // qs reads done

#pragma unroll
  for (int tf = 0; tf < 4; ++tf)
#pragma unroll
    for (int r = 0; r < 4; ++r) {
      float s = 0.f, q2 = 0.f;
#pragma unroll
      for (int cf = 0; cf < 4; ++cf) {
        const float v = acc[tf][cf][r];
        s += v; q2 += v * v;
      }
      s += __shfl_xor(s, 1); q2 += __shfl_xor(q2, 1);
      s += __shfl_xor(s, 2); q2 += __shfl_xor(q2, 2);
      s += __shfl_xor(s, 4); q2 += __shfl_xor(q2, 4);
      s += __shfl_xor(s, 8); q2 += __shfl_xor(q2, 8);
      if (l16 == 0) {
        const int tok = tf * 16 + lhi * 4 + r;
        red[(wid * 64 + tok) * 2] = s;
        red[(wid * 64 + tok) * 2 + 1] = q2;
      }
    }
  __syncthreads();

  float mean[4][4], rstd[4][4];
#pragma unroll
  for (int tf = 0; tf < 4; ++tf)
#pragma unroll
    for (int r = 0; r < 4; ++r) {
      const int tok = tf * 16 + lhi * 4 + r;
      float s = 0.f, q2 = 0.f;
#pragma unroll
      for (int cg = 0; cg < 4; ++cg) {
        s += red[(cg * 64 + tok) * 2];
        q2 += red[(cg * 64 + tok) * 2 + 1];
      }
      const float mu = s * (1.0f / 256.0f);
      const float var = q2 * (1.0f / 256.0f) - mu * mu;
      mean[tf][r] = mu;
      rstd[tf][r] = rsqrtf(var + 1e-5f);
    }

  float* ob = out + ((size_t)b * NC) * NTOK + bx * 64;
#pragma unroll
  for (int tf = 0; tf < 4; ++tf)
#pragma unroll
    for (int cf = 0; cf < 4; ++cf) {
      const int c = wid * 64 + cf * 16 + l16;
      f32x4 ov;
#pragma unroll
      for (int r = 0; r < 4; ++r)
        ov[r] = (acc[tf][cf][r] - mean[tf][r]) * rstd[tf][r] * gl[cf];
      *(f32x4*)&ob[(size_t)c * NTOK + tf * 16 + lhi * 4] = ov;
    }
}

// ---------------------------------------------------------------------------
extern "C" void kernel_launch(void* const* d_in, const int* in_sizes, int n_in,
                              void* d_out, int out_size, void* d_ws, size_t ws_size,
                              hipStream_t stream) {
  const float* x  = (const float*)d_in[0];
  const float* Wq = (const float*)d_in[1];
  const float* Wk = (const float*)d_in[2];
  const float* Wv = (const float*)d_in[3];
  const float* Wo = (const float*)d_in[4];
  const float* bo = (const float*)d_in[5];
  const float* g  = (const float*)d_in[6];
  float* out = (float*)d_out;

  char* ws = (char*)d_ws;
  unsigned short* Wswz = (unsigned short*)(ws);            // 192 KiB
  unsigned short* qg   = (unsigned short*)(ws + 262144);   // 16 MiB  [16][64][4][16][128] bf16
  unsigned short* Pp   = (unsigned short*)(ws + 17039360); // 8 MiB   [16][64][4][32][32] bf16
  float*          Sp   = (float*)(ws + 25427968);          // 512 KiB [16][64][128] f32
  float*          Pr   = (float*)(ws + 25952256);          // 2 MiB   [16][8][4096] f32
  float*          Sr   = (float*)(ws + 28049408);          // 64 KiB  [16][8][128] f32
  unsigned short* Mswz = (unsigned short*)(ws + 28377088); // 1 MiB   [16][16][4][512] bf16
  (void)ws_size; (void)in_sizes; (void)n_in; (void)out_size;

  hipLaunchKernelGGL(k0_w, dim3(24), dim3(512), 0, stream, Wq, Wk, Wv, Wswz);
  hipLaunchKernelGGL(k1_qkv, dim3(64, NB), dim3(512), 0, stream, x, Wswz, qg, Pp, Sp);
  hipLaunchKernelGGL(k2a_tree, dim3(8, NB), dim3(256), 0, stream, Pp, Sp, Pr, Sr);
  hipLaunchKernelGGL(k2bc, dim3(16, NB), dim3(256), 0, stream, Pr, Sr, Wo, Mswz);
  hipLaunchKernelGGL(k3_out, dim3(64, NB), dim3(256), 0, stream, qg, Mswz, bo, g, out);
}

// Round 16
// 75.592 us; speedup vs baseline: 1.0987x; 1.0987x over previous
//
#include <hip/hip_runtime.h>
#include <hip/hip_bf16.h>

typedef float f32x4 __attribute__((ext_vector_type(4)));
typedef short bf16x8 __attribute__((ext_vector_type(8)));
typedef unsigned short us4 __attribute__((ext_vector_type(4)));

#define NB 16
#define NC 256
#define NTOK 4096
#define NHID 128

// ---- hw bf16 converts (compiler emits v_cvt_pk_bf16_f32) ----
__device__ __forceinline__ unsigned pk2(float lo, float hi) {
  float2 f; f.x = lo; f.y = hi;
  __hip_bfloat162 h = __float22bfloat162_rn(f);
  unsigned u; __builtin_memcpy(&u, &h, 4); return u;
}
__device__ __forceinline__ uint2 pk4(f32x4 v) {
  uint2 r; r.x = pk2(v[0], v[1]); r.y = pk2(v[2], v[3]); return r;
}
__device__ __forceinline__ float bf2f(unsigned short h) {
  union { unsigned u; float f; } v; v.u = ((unsigned)h) << 16;
  return v.f;
}

// ---------------------------------------------------------------------------
// k0: W rows (Wq|Wk|Wv, fp32) -> bf16 MFMA B-frag per-lane order.
// ---------------------------------------------------------------------------
__global__ __launch_bounds__(512) void k0_w(
    const float* __restrict__ Wq, const float* __restrict__ Wk,
    const float* __restrict__ Wv, unsigned short* __restrict__ Wswz)
{
  const int mt = blockIdx.x;            // 0..23
  const int t = threadIdx.x;
  const int ks = t >> 6, l = t & 63;
  const int m = mt * 16 + (l & 15);
  const int col = ks * 32 + (l >> 4) * 8;
  const float* src = (m < 128) ? (Wq + (size_t)m * NC)
                   : (m < 256) ? (Wk + (size_t)(m - 128) * NC)
                               : (Wv + (size_t)(m - 256) * NC);
  const float4 w0 = *(const float4*)(src + col);
  const float4 w1 = *(const float4*)(src + col + 4);
  uint4 p;
  p.x = pk2(w0.x, w0.y); p.y = pk2(w0.z, w0.w);
  p.z = pk2(w1.x, w1.y); p.w = pk2(w1.z, w1.w);
  *(uint4*)&Wswz[((size_t)(mt * 8 + ks)) * 512 + l * 8] = p;
}

// ---------------------------------------------------------------------------
// k1 (proven no-spill form): per (b, 64-token tile).
// LDS 64 KB: As (32 KB) + separate postKV (32 KB). Depth-2 W prefetch with
// hoisted initial loads. (512,4): VGPR 56 + 48 AGPR, no spill.
// ---------------------------------------------------------------------------
__global__ __launch_bounds__(512, 4) void k1_qkv(
    const float* __restrict__ x, const unsigned short* __restrict__ Wswz,
    unsigned short* __restrict__ qg, unsigned short* __restrict__ Pp,
    float* __restrict__ Sp)
{
  __shared__ __align__(16) unsigned char smem[65536];
  // [0, 32768):      As [64 tok][512 B], XOR ^((tok&7)<<4)
  // [32768, 65536):  postKV [256 rows][128 B], XOR ^((row&7)<<4)

  const int tile = blockIdx.x, b = blockIdx.y;
  const int n0 = tile * 64;
  const int t = threadIdx.x;
  const int wid = t >> 6, l = t & 63;
  const int l16 = l & 15, lhi = l >> 4;
  const unsigned xr = (unsigned)((l16 & 7) << 4);

  int fr[3];
  if (wid < 4) { fr[0] = 2 * wid; fr[1] = 2 * wid + 1; fr[2] = 8 + wid; }
  else { const int w = wid - 4; fr[0] = 12 + w; fr[1] = 16 + 2 * w; fr[2] = 17 + 2 * w; }

#define WFRAG(f, kss) (*(const bf16x8*)&Wswz[((size_t)(fr[f] * 8 + (kss))) * 512 + l * 8])
#define AFRAG(tf, kss) (*(const bf16x8*)(smem + \
    (((unsigned)(((tf) * 16 + l16) * 512 + (kss) * 64 + lhi * 16)) ^ xr)))
#define PKVB(roww, boff) (smem + 32768u + \
    ((((unsigned)((roww) * 128 + (boff))) ^ (((unsigned)((roww) & 7)) << 4))))

  // ---- hoisted initial W-frag loads (land during x-stage + barrier)
  bf16x8 wA[3], wB[3], wC[3];
#pragma unroll
  for (int f = 0; f < 3; ++f) wA[f] = WFRAG(f, 0);
#pragma unroll
  for (int f = 0; f < 3; ++f) wB[f] = WFRAG(f, 1);

  // ---- stage x^T tile -> As[tok][c] bf16, XOR swizzled, b128 writes
  {
    const int cg = t >> 4;   // 8-c group 0..31
    const int tq = t & 15;   // tok quad
    const float* rp = x + (size_t)b * NC * NTOK + (size_t)(cg * 8) * NTOK + n0 + tq * 4;
    float4 rv[8];
#pragma unroll
    for (int i = 0; i < 8; ++i) rv[i] = *(const float4*)(rp + (size_t)i * NTOK);
#pragma unroll
    for (int j = 0; j < 4; ++j) {
      const int tok = tq * 4 + j;
      uint4 pv;
      pv.x = pk2(rv[0][j], rv[1][j]); pv.y = pk2(rv[2][j], rv[3][j]);
      pv.z = pk2(rv[4][j], rv[5][j]); pv.w = pk2(rv[6][j], rv[7][j]);
      *(uint4*)(smem + (((unsigned)(tok * 512 + cg * 16)) ^ ((unsigned)(tok & 7) << 4))) = pv;
    }
  }
  __syncthreads();

  // ---- GEMM: 64 toks x 3 m-frags per wave, K=256, depth-2 W prefetch
  f32x4 acc[4][3];
#pragma unroll
  for (int i = 0; i < 4; ++i)
#pragma unroll
    for (int j = 0; j < 3; ++j) acc[i][j] = 0;

#pragma unroll
  for (int ks = 0; ks < 8; ++ks) {
    if (ks < 6) {
#pragma unroll
      for (int f = 0; f < 3; ++f) wC[f] = WFRAG(f, ks + 2);  // depth-2 prefetch
    }
#pragma unroll
    for (int tf = 0; tf < 4; ++tf) {
      const bf16x8 a = AFRAG(tf, ks);
#pragma unroll
      for (int f = 0; f < 3; ++f)
        acc[tf][f] = __builtin_amdgcn_mfma_f32_16x16x32_bf16(a, wA[f], acc[tf][f], 0, 0, 0);
    }
#pragma unroll
    for (int f = 0; f < 3; ++f) { wA[f] = wB[f]; wB[f] = wC[f]; }  // rotate (renamed)
  }

  // ---- register epilogue; retire to postKV (separate region) / global
  const float qscale = 0.1767766952966369f;  // 32^-0.5
  if (wid < 4) {
#pragma unroll
    for (int tf = 0; tf < 4; ++tf)
#pragma unroll
      for (int r = 0; r < 4; ++r) {
        const float a0 = acc[tf][0][r], a1 = acc[tf][1][r];
        float mx = fmaxf(a0, a1);
        mx = fmaxf(mx, __shfl_xor(mx, 1));
        mx = fmaxf(mx, __shfl_xor(mx, 2));
        mx = fmaxf(mx, __shfl_xor(mx, 4));
        mx = fmaxf(mx, __shfl_xor(mx, 8));
        const float e0 = __expf(a0 - mx), e1 = __expf(a1 - mx);
        float s = e0 + e1;
        s += __shfl_xor(s, 1); s += __shfl_xor(s, 2);
        s += __shfl_xor(s, 4); s += __shfl_xor(s, 8);
        const float inv = qscale / s;
        acc[tf][0][r] = e0 * inv;
        acc[tf][1][r] = e1 * inv;
      }
    float s = 0.f;
#pragma unroll
    for (int tf = 0; tf < 4; ++tf)
#pragma unroll
      for (int r = 0; r < 4; ++r) {
        const float e = __expf(acc[tf][2][r]);
        acc[tf][2][r] = e;
        s += e;
      }
    s += __shfl_xor(s, 16);
    s += __shfl_xor(s, 32);
    if (l < 16) Sp[((size_t)b * 64 + tile) * 128 + (fr[2] - 8) * 16 + l16] = s;

    unsigned short* qt = qg + ((size_t)(b * 64 + tile)) * 8192;
#pragma unroll
    for (int f = 0; f < 2; ++f) {
      const int j = fr[f] * 16 + l16;
#pragma unroll
      for (int tf = 0; tf < 4; ++tf)
        *(uint2*)&qt[tf * 2048 + j * 16 + lhi * 4] = pk4(acc[tf][f]);
    }
    const int row = (fr[2] - 8) * 16 + l16;
#pragma unroll
    for (int tf = 0; tf < 4; ++tf)
      *(uint2*)PKVB(row, tf * 32 + lhi * 8) = pk4(acc[tf][2]);
  } else {
    float s = 0.f;
#pragma unroll
    for (int tf = 0; tf < 4; ++tf)
#pragma unroll
      for (int r = 0; r < 4; ++r) {
        const float e = __expf(acc[tf][0][r]);
        acc[tf][0][r] = e;
        s += e;
      }
    s += __shfl_xor(s, 16);
    s += __shfl_xor(s, 32);
    if (l < 16) Sp[((size_t)b * 64 + tile) * 128 + (fr[0] - 8) * 16 + l16] = s;

    const int rowk = (fr[0] - 8) * 16 + l16;
    const int rowv1 = 128 + (fr[1] - 16) * 16 + l16;
    const int rowv2 = 128 + (fr[2] - 16) * 16 + l16;
#pragma unroll
    for (int tf = 0; tf < 4; ++tf) {
      *(uint2*)PKVB(rowk, tf * 32 + lhi * 8) = pk4(acc[tf][0]);
      *(uint2*)PKVB(rowv1, tf * 32 + lhi * 8) = pk4(acc[tf][1]);
      *(uint2*)PKVB(rowv2, tf * 32 + lhi * 8) = pk4(acc[tf][2]);
    }
  }
  __syncthreads();  // postKV complete

  // ---- context partials: all 8 waves, wave = (h = wid&3, d-half = wid>>2)
  {
    const int h = wid & 3, dh = wid >> 2;
    f32x4 ca[2];
    ca[0] = 0; ca[1] = 0;
#pragma unroll
    for (int ks2 = 0; ks2 < 2; ++ks2) {
      const int rowa = h * 32 + dh * 16 + l16;
      const bf16x8 ae = *(const bf16x8*)PKVB(rowa, ks2 * 64 + lhi * 16);
#pragma unroll
      for (int e = 0; e < 2; ++e) {
        const int rowb = 128 + h * 32 + e * 16 + l16;
        const bf16x8 be = *(const bf16x8*)PKVB(rowb, ks2 * 64 + lhi * 16);
        ca[e] = __builtin_amdgcn_mfma_f32_16x16x32_bf16(ae, be, ca[e], 0, 0, 0);
      }
    }
    unsigned short* pb = Pp + (((size_t)b * 64 + tile) * 4 + h) * 1024;
#pragma unroll
    for (int e = 0; e < 2; ++e)
      *(uint2*)&pb[(e * 16 + l16) * 32 + dh * 16 + lhi * 4] = pk4(ca[e]);
  }
}

// ---------------------------------------------------------------------------
// k2a: tree stage 1. Grid (8 seg, 16 b).
// ---------------------------------------------------------------------------
__global__ __launch_bounds__(256) void k2a_tree(
    const unsigned short* __restrict__ Pp, const float* __restrict__ Sp,
    float* __restrict__ Pr, float* __restrict__ Sr)
{
  const int seg = blockIdx.x, b = blockIdx.y;
  const int t = threadIdx.x;
  const unsigned short* pb = Pp + ((size_t)b * 64 + seg * 8) * 4096;
  f32x4 a[4];
#pragma unroll
  for (int i = 0; i < 4; ++i) a[i] = 0;
#pragma unroll
  for (int tile = 0; tile < 8; ++tile) {
#pragma unroll
    for (int i = 0; i < 4; ++i) {
      const us4 v = *(const us4*)&pb[tile * 4096 + i * 1024 + t * 4];
      a[i][0] += bf2f(v[0]); a[i][1] += bf2f(v[1]);
      a[i][2] += bf2f(v[2]); a[i][3] += bf2f(v[3]);
    }
  }
  float* pr = Pr + ((size_t)b * 8 + seg) * 4096;
#pragma unroll
  for (int i = 0; i < 4; ++i) *(f32x4*)&pr[i * 1024 + t * 4] = a[i];

  if (t < 128) {
    float s = 0.f;
    const float* sb = Sp + ((size_t)b * 64 + seg * 8) * 128 + t;
#pragma unroll
    for (int i = 0; i < 8; ++i) s += sb[i * 128];
    Sr[((size_t)b * 8 + seg) * 128 + t] = s;
  }
}

// ---------------------------------------------------------------------------
// k2bc: tree stage 2 + normalize + M build. Grid (16 ct, 16 b).
// ---------------------------------------------------------------------------
__global__ __launch_bounds__(256) void k2bc(
    const float* __restrict__ Pr, const float* __restrict__ Sr,
    const float* __restrict__ Wo, unsigned short* __restrict__ Mswz)
{
  __shared__ float CnS[4096];
  __shared__ float Ss[128];
  const int ct = blockIdx.x, b = blockIdx.y;
  const int t = threadIdx.x;

  if (t < 128) {
    float s = 0.f;
    const float* sb = Sr + (size_t)b * 8 * 128 + t;
#pragma unroll
    for (int i = 0; i < 8; ++i) s += sb[i * 128];
    Ss[t] = 1.0f / (s * 4096.0f);
  }
  __syncthreads();

#pragma unroll
  for (int i = 0; i < 16; ++i) {
    const int idx = t + 256 * i;
    float a = 0.f;
#pragma unroll
    for (int seg = 0; seg < 8; ++seg) a += Pr[((size_t)b * 8 + seg) * 4096 + idx];
    CnS[idx] = a * Ss[((idx >> 10) << 5) | (idx & 31)];
  }
  __syncthreads();

  const int ks = t >> 6, l = t & 63;  // ks = h
  const int c = ct * 16 + (l & 15);
  const int d0 = (l >> 4) * 8;
  const float* wr = Wo + (size_t)c * NHID + ks * 32;
  const float* cb = &CnS[ks * 1024];
  f32x4 s0 = 0, s1 = 0;
#pragma unroll 8
  for (int e = 0; e < 32; ++e) {
    const float w = wr[e];
    const f32x4 c0 = *(const f32x4*)&cb[e * 32 + d0];
    const f32x4 c1 = *(const f32x4*)&cb[e * 32 + d0 + 4];
#pragma unroll
    for (int j = 0; j < 4; ++j) { s0[j] += w * c0[j]; s1[j] += w * c1[j]; }
  }
  uint4 p;
  p.x = pk2(s0[0], s0[1]); p.y = pk2(s0[2], s0[3]);
  p.z = pk2(s1[0], s1[1]); p.w = pk2(s1[2], s1[3]);
  *(uint4*)&Mswz[(((size_t)b * 16 + ct) * 4 + ks) * 512 + l * 8] = p;
}

// ---------------------------------------------------------------------------
// k3 (proven one-tile form, grid (64,16)): async global_load_lds staging.
// ---------------------------------------------------------------------------
__global__ __launch_bounds__(256, 3) void k3_out(
    const unsigned short* __restrict__ qg, const unsigned short* __restrict__ Mswz,
    const float* __restrict__ bo, const float* __restrict__ g, float* __restrict__ out)
{
  __shared__ __align__(16) unsigned char qs[16384];
  __shared__ float red[4 * 64 * 2];
  const int bx = blockIdx.x, b = blockIdx.y;
  const int t = threadIdx.x;
  const int wid = t >> 6, l = t & 63;
  const int l16 = l & 15, lhi = l >> 4;

  // async stage q tile (16 KB): per (wave, chunk), lds = base + lane*16
  {
    const unsigned char* gq = (const unsigned char*)(qg + ((size_t)(b * 64 + bx)) * 8192);
#pragma unroll
    for (int i = 0; i < 4; ++i)
      __builtin_amdgcn_global_load_lds(
          (const unsigned int*)(gq + i * 4096 + (wid * 64 + l) * 16),
          (unsigned int*)(qs + i * 4096 + wid * 1024),
          16, 0, 0);
  }

  bf16x8 mf[4][4];
#pragma unroll
  for (int cf = 0; cf < 4; ++cf)
#pragma unroll
    for (int ks = 0; ks < 4; ++ks)
      mf[cf][ks] = *(const bf16x8*)&Mswz[(((size_t)b * 16 + wid * 4 + cf) * 4 + ks) * 512 + l * 8];

  float bol[4], gl[4];
#pragma unroll
  for (int cf = 0; cf < 4; ++cf) {
    const int c = wid * 64 + cf * 16 + l16;
    bol[cf] = bo[c]; gl[cf] = g[c];
  }

  f32x4 acc[4][4];
#pragma unroll
  for (int i = 0; i < 4; ++i)
#pragma unroll
    for (int j = 0; j < 4; ++j) acc[i][j] = 0;

  __syncthreads();  // qs staged (vmcnt drained by barrier)

#pragma unroll
  for (int tf = 0; tf < 4; ++tf) {
    bf16x8 qf[4];
#pragma unroll
    for (int ks = 0; ks < 4; ++ks) {
      bf16x8 qv;
#pragma unroll
      for (int jj = 0; jj < 8; ++jj) {
        const unsigned short u = *(const unsigned short*)(qs +
            tf * 4096 + (ks * 32 + lhi * 8 + jj) * 32 + l16 * 2);
        qv[jj] = (short)u;
      }
      qf[ks] = qv;
    }
#pragma unroll
    for (int ks = 0; ks < 4; ++ks)
#pragma unroll
      for (int cf = 0; cf < 4; ++cf)
        acc[tf][cf] = __builtin_amdgcn_mfma_f32_16x16x32_bf16(qf[ks], mf[cf][ks], acc[tf][cf], 0, 0, 0);
  }

#pragma unroll
  for (int tf = 0; tf < 4; ++tf)
#pragma unroll
    for (int cf = 0; cf < 4; ++cf)
#pragma unroll
      for (int r = 0; r < 4; ++r) acc[tf][cf][r] += bol[cf];

  __syncthreads();  // qs reads done

#pragma unroll
  for (int tf = 0; tf < 4; ++tf)
#pragma unroll
    for (int r = 0; r < 4; ++r) {
      float s = 0.f, q2 = 0.f;
#pragma unroll
      for (int cf = 0; cf < 4; ++cf) {
        const float v = acc[tf][cf][r];
        s += v; q2 += v * v;
      }
      s += __shfl_xor(s, 1); q2 += __shfl_xor(q2, 1);
      s += __shfl_xor(s, 2); q2 += __shfl_xor(q2, 2);
      s += __shfl_xor(s, 4); q2 += __shfl_xor(q2, 4);
      s += __shfl_xor(s, 8); q2 += __shfl_xor(q2, 8);
      if (l16 == 0) {
        const int tok = tf * 16 + lhi * 4 + r;
        red[(wid * 64 + tok) * 2] = s;
        red[(wid * 64 + tok) * 2 + 1] = q2;
      }
    }
  __syncthreads();

  float mean[4][4], rstd[4][4];
#pragma unroll
  for (int tf = 0; tf < 4; ++tf)
#pragma unroll
    for (int r = 0; r < 4; ++r) {
      const int tok = tf * 16 + lhi * 4 + r;
      float s = 0.f, q2 = 0.f;
#pragma unroll
      for (int cg = 0; cg < 4; ++cg) {
        s += red[(cg * 64 + tok) * 2];
        q2 += red[(cg * 64 + tok) * 2 + 1];
      }
      const float mu = s * (1.0f / 256.0f);
      const float var = q2 * (1.0f / 256.0f) - mu * mu;
      mean[tf][r] = mu;
      rstd[tf][r] = rsqrtf(var + 1e-5f);
    }

  float* ob = out + ((size_t)b * NC) * NTOK + bx * 64;
#pragma unroll
  for (int tf = 0; tf < 4; ++tf)
#pragma unroll
    for (int cf = 0; cf < 4; ++cf) {
      const int c = wid * 64 + cf * 16 + l16;
      f32x4 ov;
#pragma unroll
      for (int r = 0; r < 4; ++r)
        ov[r] = (acc[tf][cf][r] - mean[tf][r]) * rstd[tf][r] * gl[cf];
      *(f32x4*)&ob[(size_t)c * NTOK + tf * 16 + lhi * 4] = ov;
    }
}

// ---------------------------------------------------------------------------
extern "C" void kernel_launch(void* const* d_in, const int* in_sizes, int n_in,
                              void* d_out, int out_size, void* d_ws, size_t ws_size,
                              hipStream_t stream) {
  const float* x  = (const float*)d_in[0];
  const float* Wq = (const float*)d_in[1];
  const float* Wk = (const float*)d_in[2];
  const float* Wv = (const float*)d_in[3];
  const float* Wo = (const float*)d_in[4];
  const float* bo = (const float*)d_in[5];
  const float* g  = (const float*)d_in[6];
  float* out = (float*)d_out;

  char* ws = (char*)d_ws;
  unsigned short* Wswz = (unsigned short*)(ws);            // 192 KiB
  unsigned short* qg   = (unsigned short*)(ws + 262144);   // 16 MiB  [16][64][4][128][16] bf16
  unsigned short* Pp   = (unsigned short*)(ws + 17039360); // 8 MiB   [16][64][4][32][32] bf16
  float*          Sp   = (float*)(ws + 25427968);          // 512 KiB [16][64][128] f32
  float*          Pr   = (float*)(ws + 25952256);          // 2 MiB   [16][8][4096] f32
  float*          Sr   = (float*)(ws + 28049408);          // 64 KiB  [16][8][128] f32
  unsigned short* Mswz = (unsigned short*)(ws + 28377088); // 1 MiB   [16][16][4][512] bf16
  (void)ws_size; (void)in_sizes; (void)n_in; (void)out_size;

  hipLaunchKernelGGL(k0_w, dim3(24), dim3(512), 0, stream, Wq, Wk, Wv, Wswz);
  hipLaunchKernelGGL(k1_qkv, dim3(64, NB), dim3(512), 0, stream, x, Wswz, qg, Pp, Sp);
  hipLaunchKernelGGL(k2a_tree, dim3(8, NB), dim3(256), 0, stream, Pp, Sp, Pr, Sr);
  hipLaunchKernelGGL(k2bc, dim3(16, NB), dim3(256), 0, stream, Pr, Sr, Wo, Mswz);
  hipLaunchKernelGGL(k3_out, dim3(64, NB), dim3(256), 0, stream, qg, Mswz, bo, g, out);
}